// Round 11
// baseline (6169.102 us; speedup 1.0000x reference)
//
#include <hip/hip_runtime.h>

#define NHID   128
#define NSTEPS 512
#define NSAMP  4096
#define SPB    16
#define BS     512
#define NBLK   (NSAMP / SPB)          // 256 blocks, 1 per CU
#define KL     20                     // k4-chunks staged in LDS (of 32)
#define SAMP_ELEMS (NSAMP * NSTEPS)
#define WZR_FLOATS (32 * 128 * 8)     // (wz,wr) interleaved: 128 KB
#define WH_FLOATS  (32 * 128 * 4)     // wh plane: 64 KB
#define WS_FLOATS  (WZR_FLOATS + WH_FLOATS)

typedef float v2f __attribute__((ext_vector_type(2)));
typedef float v4f __attribute__((ext_vector_type(4)));

// acc.lo += w.lo*h ; acc.hi += w.hi*h
// H is a 64-bit SGPR pair whose LOW half holds h; op_sel_hi[src1]=0
// broadcasts the low half to both lanes (high half is don't-care).
#define PKB(A, W, H64) \
    asm("v_pk_fma_f32 %0, %1, %2, %0 op_sel:[0,0,0] op_sel_hi:[1,0,1]" \
        : "+v"(A) : "v"(W), "s"(H64))

template<int IMM>
__device__ __forceinline__ float swz(float x) {
    return __int_as_float(__builtin_amdgcn_ds_swizzle(__float_as_int(x), IMM));
}
__device__ __forceinline__ unsigned long long rdl64(float f, int l) {
    return (unsigned long long)(unsigned)__builtin_amdgcn_readlane(__float_as_int(f), l);
}

// ws layout: wzr[(k4*128+c)*8 + 2*kk + g] = rk[(4k4+kk)*384 + g*128 + c], g in {z,r}
//            wh [WZR + (k4*128+c)*4 + kk] = rk[(4k4+kk)*384 + 256 + c]
__global__ __launch_bounds__(256)
void pack_w_kernel(const float* __restrict__ rk, float* __restrict__ ws) {
    const int i = blockIdx.x * 256 + threadIdx.x;
    if (i < WZR_FLOATS) {
        const int g  = i & 1;
        const int kk = (i >> 1) & 3;
        const int c  = (i >> 3) & 127;
        const int k4 = i >> 10;
        ws[i] = rk[(4 * k4 + kk) * 384 + g * NHID + c];
    } else if (i < WS_FLOATS) {
        const int ih = i - WZR_FLOATS;
        const int kk = ih & 3;
        const int c  = (ih >> 2) & 127;
        const int k4 = ih >> 9;
        ws[i] = rk[(4 * k4 + kk) * 384 + 256 + c];
    }
}

template<int TR>
__global__ __launch_bounds__(BS, 2)
void vmc_gru_kernel(const float* __restrict__ gk,   // (2, 384)
                    const float* __restrict__ rk,   // (128, 384)
                    const float* __restrict__ gb,   // (2, 384)
                    const float* __restrict__ dw,   // (128, 2)
                    const float* __restrict__ db,   // (2,)
                    const float* __restrict__ u,    // (4096, 512)
                    const float* __restrict__ ws,   // packed wzr + wh
                    float* __restrict__ out)        // samples then logp
{
    __shared__ v4f   szr[KL * 128 * 2];       // 80 KB
    __shared__ v4f   swh[KL * 128];           // 40 KB
    __shared__ float hsm[2][4][NHID][4];      // 16 KB, h[buf][quad][k][4 samples]
    __shared__ float part[2][8][4][8];        // 8 KB

    const int tid  = threadIdx.x;
    const int lane = tid & 63;
    const int wv   = tid >> 6;
    const int half = wv & 1;
    const int q    = wv >> 1;
    const int c    = half * 64 + lane;
    const int sbase = blockIdx.x * SPB + q * 4;

    if (TR) {
        const v4f* g0 = (const v4f*)ws;
        for (int i = tid; i < KL * 128 * 2; i += BS) szr[i] = g0[i];
        const v4f* g1 = (const v4f*)(ws + WZR_FLOATS);
        for (int i = tid; i < KL * 128; i += BS) swh[i] = g1[i];
    }
    for (int i = tid; i < 2 * 4 * NHID * 4; i += BS) (&hsm[0][0][0][0])[i] = 0.0f;
    __syncthreads();

    // per-channel constants
    const float brz = gb[384 + c];
    const float brr = gb[384 + 128 + c];
    const float brh = gb[384 + 256 + c];
    const float xzI = gb[c],       xz0c = xzI + gk[c],       xz1c = xzI + gk[384 + c];
    const float xrI = gb[128 + c], xr0c = xrI + gk[128 + c], xr1c = xrI + gk[384 + 128 + c];
    const float xhI = gb[256 + c], xh0c = xhI + gk[256 + c], xh1c = xhI + gk[384 + 256 + c];
    const float dwc0 = dw[c * 2], dwc1 = dw[c * 2 + 1];
    const float db0 = db[0], db1 = db[1];

    const v4f* lzr = szr + c * 2;                       // + k4*256
    const v4f* lwh = swh + c;                           // + k4*128
    const v4f* gzr = (const v4f*)ws + c * 2;            // + k4*256
    const v4f* gwh = (const v4f*)(ws + WZR_FLOATS) + c; // + k4*128
    const float* rkc = rk + c;

    int   pv[4] = {0, 0, 0, 0};
    float lg[4] = {0.f, 0.f, 0.f, 0.f};
    float pr[4] = {1.f, 1.f, 1.f, 1.f};
    int cur = 0;

    for (int t = 0; t < NSTEPS; ++t) {
        float uv[4];
        #pragma unroll
        for (int j = 0; j < 4; ++j)
            uv[j] = u[(size_t)(sbase + j) * NSTEPS + t];

        // cooperative h: lane l holds h[k=l][quad][4 samples] (hA), k=64+l (hB)
        const v4f hA = *(const v4f*)&hsm[cur][q][lane][0];
        const v4f hB = *(const v4f*)&hsm[cur][q][64 + lane][0];

        // accumulators: zrj = (az,ar) for sample j; ahj scalar. bias-init.
        v2f zr0 = {brz, brr}, zr1 = {brz, brr}, zr2 = {brz, brr}, zr3 = {brz, brr};
        float ah0 = brh, ah1 = brh, ah2 = brh, ah3 = brh;

// one k-step: 4 readlane + 4 pk_fma(z,r) + 4 fmaf(h-gate); chains bit-identical
#define GK(WP, WH1, HSRC, KLANE) do {                                   \
    const unsigned long long s0_ = rdl64((HSRC).x, (KLANE));            \
    const unsigned long long s1_ = rdl64((HSRC).y, (KLANE));            \
    const unsigned long long s2_ = rdl64((HSRC).z, (KLANE));            \
    const unsigned long long s3_ = rdl64((HSRC).w, (KLANE));            \
    PKB(zr0, WP, s0_); PKB(zr1, WP, s1_);                               \
    PKB(zr2, WP, s2_); PKB(zr3, WP, s3_);                               \
    ah0 = fmaf(WH1, __int_as_float((int)s0_), ah0);                     \
    ah1 = fmaf(WH1, __int_as_float((int)s1_), ah1);                     \
    ah2 = fmaf(WH1, __int_as_float((int)s2_), ah2);                     \
    ah3 = fmaf(WH1, __int_as_float((int)s3_), ah3);                     \
} while (0)

#define GK4(ZRA, ZRB, WHQ, HSRC, KB) do {                               \
    const v2f wA = (ZRA).xy, wB = (ZRA).zw;                             \
    const v2f wC = (ZRB).xy, wD = (ZRB).zw;                             \
    GK(wA, (WHQ).x, HSRC, (KB) + 0);                                    \
    GK(wB, (WHQ).y, HSRC, (KB) + 1);                                    \
    GK(wC, (WHQ).z, HSRC, (KB) + 2);                                    \
    GK(wD, (WHQ).w, HSRC, (KB) + 3);                                    \
} while (0)

        if (TR) {
            #pragma unroll 4
            for (int k4 = 0; k4 < 16; ++k4) {          // W LDS, h from hA
                const v4f zrA = lzr[k4 * 256];
                const v4f zrB = lzr[k4 * 256 + 1];
                const v4f whq = lwh[k4 * 128];
                GK4(zrA, zrB, whq, hA, k4 * 4);
            }
            #pragma unroll 4
            for (int k4 = 16; k4 < KL; ++k4) {         // W LDS, h from hB
                const v4f zrA = lzr[k4 * 256];
                const v4f zrB = lzr[k4 * 256 + 1];
                const v4f whq = lwh[k4 * 128];
                GK4(zrA, zrB, whq, hB, k4 * 4 - 64);
            }
            #pragma unroll 4
            for (int k4 = KL; k4 < 32; ++k4) {         // W global (L1/L2), h from hB
                const v4f zrA = gzr[k4 * 256];
                const v4f zrB = gzr[k4 * 256 + 1];
                const v4f whq = gwh[k4 * 128];
                GK4(zrA, zrB, whq, hB, k4 * 4 - 64);
            }
        } else {
            #pragma unroll 4
            for (int k = 0; k < NHID; ++k) {
                const v4f hsrc = (k < 64) ? hA : hB;
                const int l = k & 63;
                const float h0 = __int_as_float((int)rdl64(hsrc.x, l));
                const float h1 = __int_as_float((int)rdl64(hsrc.y, l));
                const float h2 = __int_as_float((int)rdl64(hsrc.z, l));
                const float h3 = __int_as_float((int)rdl64(hsrc.w, l));
                const float wzs = rkc[k * 384];
                const float wrs = rkc[k * 384 + 128];
                const float whs = rkc[k * 384 + 256];
                zr0.x = fmaf(wzs, h0, zr0.x); zr0.y = fmaf(wrs, h0, zr0.y);
                zr1.x = fmaf(wzs, h1, zr1.x); zr1.y = fmaf(wrs, h1, zr1.y);
                zr2.x = fmaf(wzs, h2, zr2.x); zr2.y = fmaf(wrs, h2, zr2.y);
                zr3.x = fmaf(wzs, h3, zr3.x); zr3.y = fmaf(wrs, h3, zr3.y);
                ah0 = fmaf(whs, h0, ah0); ah1 = fmaf(whs, h1, ah1);
                ah2 = fmaf(whs, h2, ah2); ah3 = fmaf(whs, h3, ah3);
            }
        }
#undef GK4
#undef GK

        const float az[4] = {zr0.x, zr1.x, zr2.x, zr3.x};
        const float ar[4] = {zr0.y, zr1.y, zr2.y, zr3.y};
        const float ah[4] = {ah0, ah1, ah2, ah3};

        // ---- gates + state update (h_old for channel c is lane-local in hA/hB)
        const v4f ho = half ? hB : hA;
        const float hov[4] = {ho.x, ho.y, ho.z, ho.w};
        float hn[4], p0s[4], p1s[4];
        #pragma unroll
        for (int j = 0; j < 4; ++j) {
            float xz = pv[j] ? xz1c : xz0c;
            float xr = pv[j] ? xr1c : xr0c;
            float xh = pv[j] ? xh1c : xh0c;
            if (t == 0) { xz = xzI; xr = xrI; xh = xhI; }
            const float z  = 1.0f / (1.0f + expf(-(xz + az[j])));
            const float r  = 1.0f / (1.0f + expf(-(xr + ar[j])));
            const float hc = tanhf(xh + r * ah[j]);
            const float hnew = z * hov[j] + (1.0f - z) * hc;
            hn[j] = hnew;
            p0s[j] = hnew * dwc0;
            p1s[j] = hnew * dwc1;
        }
        *(v4f*)&hsm[cur ^ 1][q][c][0] = (v4f){hn[0], hn[1], hn[2], hn[3]};

        // butterfly over channel bits 0..3 (lane bits 0..3): same tree as R8
        #pragma unroll
        for (int j = 0; j < 4; ++j) {
            p0s[j] += swz<0x041F>(p0s[j]);  p1s[j] += swz<0x041F>(p1s[j]);
            p0s[j] += swz<0x081F>(p0s[j]);  p1s[j] += swz<0x081F>(p1s[j]);
            p0s[j] += swz<0x101F>(p0s[j]);  p1s[j] += swz<0x101F>(p1s[j]);
            p0s[j] += swz<0x201F>(p0s[j]);  p1s[j] += swz<0x201F>(p1s[j]);
        }
        const int pb = t & 1;
        if ((lane & 15) == 0) {
            const int g = lane >> 4;
            *(float4*)&part[pb][wv][g][0] = make_float4(p0s[0], p0s[1], p0s[2], p0s[3]);
            *(float4*)&part[pb][wv][g][4] = make_float4(p1s[0], p1s[1], p1s[2], p1s[3]);
        }
        __syncthreads();   // single barrier: h_new + partials visible

        // ---- fold 8 partials (channels ascending, same order as R8)
        float l0[4] = {db0, db0, db0, db0};
        float l1[4] = {db1, db1, db1, db1};
        #pragma unroll
        for (int w = 0; w < 8; ++w) {
            const int hw = w >> 2, g = w & 3;
            const float4 a = *(const float4*)&part[pb][q * 2 + hw][g][0];
            const float4 b = *(const float4*)&part[pb][q * 2 + hw][g][4];
            l0[0] += a.x; l0[1] += a.y; l0[2] += a.z; l0[3] += a.w;
            l1[0] += b.x; l1[1] += b.y; l1[2] += b.z; l1[3] += b.w;
        }

        // ---- softmax / sample / logp (redundant per thread for its quad)
        #pragma unroll
        for (int j = 0; j < 4; ++j) {
            const float mx = fmaxf(l0[j], l1[j]);
            const float e0 = expf(l0[j] - mx);
            const float e1 = expf(l1[j] - mx);
            const float inv = 1.0f / (e0 + e1);
            const float p1v = e1 * inv;
            const int st = (uv[j] < p1v) ? 1 : 0;
            const float psel = st ? p1v : (e0 * inv);
            pr[j] *= (psel + 1e-10f);
            pv[j] = st;
            if (lane == 0 && half == 0)
                out[(size_t)(sbase + j) * NSTEPS + t] = (float)st;
        }
        if ((t & 7) == 7) {
            #pragma unroll
            for (int j = 0; j < 4; ++j) { lg[j] += logf(pr[j]); pr[j] = 1.0f; }
        }
        cur ^= 1;
    }

    if (lane == 0 && half == 0) {
        #pragma unroll
        for (int j = 0; j < 4; ++j)
            out[SAMP_ELEMS + sbase + j] = lg[j];
    }
}

extern "C" void kernel_launch(void* const* d_in, const int* in_sizes, int n_in,
                              void* d_out, int out_size, void* d_ws, size_t ws_size,
                              hipStream_t stream) {
    const float* gk = (const float*)d_in[0];
    const float* rk = (const float*)d_in[1];
    const float* gb = (const float*)d_in[2];
    const float* dw = (const float*)d_in[3];
    const float* db = (const float*)d_in[4];
    const float* u  = (const float*)d_in[5];
    float* out = (float*)d_out;

    if (ws_size >= (size_t)WS_FLOATS * sizeof(float)) {
        float* ws = (float*)d_ws;
        pack_w_kernel<<<(WS_FLOATS + 255) / 256, 256, 0, stream>>>(rk, ws);
        vmc_gru_kernel<1><<<NBLK, BS, 0, stream>>>(gk, rk, gb, dw, db, u, ws, out);
    } else {
        vmc_gru_kernel<0><<<NBLK, BS, 0, stream>>>(gk, rk, gb, dw, db, u, rk, out);
    }
}

// Round 12
// 4298.082 us; speedup vs baseline: 1.4353x; 1.4353x over previous
//
#include <hip/hip_runtime.h>

#define NHID   128
#define NSTEPS 512
#define NSAMP  4096
#define SPB    16
#define BS     512
#define NBLK   (NSAMP / SPB)          // 256 blocks, 1 per CU
#define KL     12                     // k4-chunks of W staged in LDS (of 32)
#define SAMP_ELEMS (NSAMP * NSTEPS)
#define PLANE_V4   (32 * 128)         // v4f per plane
#define WPK_FLOATS (3 * PLANE_V4 * 4) // 49152 floats = 192 KB

typedef float v2f __attribute__((ext_vector_type(2)));
typedef float v4f __attribute__((ext_vector_type(4)));

// v_pk_fma_f32 with src0-half broadcast (proven in R8):
// PKE: acc.lo += w.lo*h.lo ; acc.hi += w.lo*h.hi   (broadcast LOW half of W pair)
#define PKE(ACC, W2, H2) \
    asm("v_pk_fma_f32 %0, %1, %2, %0 op_sel:[0,0,0] op_sel_hi:[0,1,1]" \
        : "+v"(ACC) : "v"(W2), "v"(H2))
// PKO: acc.lo += w.hi*h.lo ; acc.hi += w.hi*h.hi   (broadcast HIGH half of W pair)
#define PKO(ACC, W2, H2) \
    asm("v_pk_fma_f32 %0, %1, %2, %0 op_sel:[1,0,0] op_sel_hi:[1,1,1]" \
        : "+v"(ACC) : "v"(W2), "v"(H2))

template<int IMM>
__device__ __forceinline__ float swz(float x) {
    return __int_as_float(__builtin_amdgcn_ds_swizzle(__float_as_int(x), IMM));
}

// Three planes, each [k4][c] of v4f (16B per (k4,c), contiguous across c):
//   pA[k4][c] = (wz[4k4],   wr[4k4],   wz[4k4+1], wr[4k4+1]) (c)
//   pB[k4][c] = (wz[4k4+2], wr[4k4+2], wz[4k4+3], wr[4k4+3]) (c)
//   pH[k4][c] = (wh[4k4], wh[4k4+1], wh[4k4+2], wh[4k4+3]) (c)
__global__ __launch_bounds__(256)
void pack_w_kernel(const float* __restrict__ rk, float* __restrict__ ws) {
    const int i = blockIdx.x * 256 + threadIdx.x;
    if (i >= WPK_FLOATS) return;
    const int plane = i / (PLANE_V4 * 4);
    const int r     = i - plane * (PLANE_V4 * 4);
    const int e  = r & 3;
    const int c  = (r >> 2) & 127;
    const int k4 = r >> 9;
    float v;
    if (plane == 2) {
        v = rk[(4 * k4 + e) * 384 + 256 + c];
    } else {
        const int koff = plane * 2 + (e >> 1);
        const int gate = e & 1;                  // 0=z, 1=r
        v = rk[(4 * k4 + koff) * 384 + gate * NHID + c];
    }
    ws[i] = v;
}

// one k4 = 4 k-steps, 24 pk_fma (48 MACs); chains bias-init + k-ascending
#define K4STEP(ZRA, ZRB, WHQ, H0, H1, H2, H3) do {                        \
    const v2f zA = (ZRA).xy, zB = (ZRA).zw;                               \
    const v2f zC = (ZRB).xy, zD = (ZRB).zw;                               \
    const v2f wL = (WHQ).xy, wH = (WHQ).zw;                               \
    const v2f a01 = (H0).xy, a23 = (H0).zw;                               \
    const v2f b01 = (H1).xy, b23 = (H1).zw;                               \
    const v2f c01 = (H2).xy, c23 = (H2).zw;                               \
    const v2f d01 = (H3).xy, d23 = (H3).zw;                               \
    PKE(az01, zA, a01); PKO(ar01, zA, a01);                               \
    PKE(az23, zA, a23); PKO(ar23, zA, a23);                               \
    PKE(ah01, wL, a01); PKE(ah23, wL, a23);                               \
    PKE(az01, zB, b01); PKO(ar01, zB, b01);                               \
    PKE(az23, zB, b23); PKO(ar23, zB, b23);                               \
    PKO(ah01, wL, b01); PKO(ah23, wL, b23);                               \
    PKE(az01, zC, c01); PKO(ar01, zC, c01);                               \
    PKE(az23, zC, c23); PKO(ar23, zC, c23);                               \
    PKE(ah01, wH, c01); PKE(ah23, wH, c23);                               \
    PKE(az01, zD, d01); PKO(ar01, zD, d01);                               \
    PKE(az23, zD, d23); PKO(ar23, zD, d23);                               \
    PKO(ah01, wH, d01); PKO(ah23, wH, d23);                               \
} while (0)

template<int TR>
__global__ __launch_bounds__(BS, 2)
void vmc_gru_kernel(const float* __restrict__ gk,   // (2, 384)
                    const float* __restrict__ rk,   // (128, 384)
                    const float* __restrict__ gb,   // (2, 384)
                    const float* __restrict__ dw,   // (128, 2)
                    const float* __restrict__ db,   // (2,)
                    const float* __restrict__ u,    // (4096, 512)
                    const float* __restrict__ ws,   // packed planes
                    float* __restrict__ out)        // samples then logp
{
    __shared__ v4f   sA[KL * 128];            // 24 KB
    __shared__ v4f   sB[KL * 128];            // 24 KB
    __shared__ v4f   sH[KL * 128];            // 24 KB
    __shared__ float hsm[2][4][NHID][4];      // 16 KB, h[buf][quad][k][4 samples]
    __shared__ float part[2][8][4][8];        // 2 KB

    const int tid  = threadIdx.x;
    const int lane = tid & 63;
    const int wv   = tid >> 6;
    const int half = wv & 1;
    const int q    = wv >> 1;
    const int c    = half * 64 + lane;
    const int sbase = blockIdx.x * SPB + q * 4;

    if (TR) {
        const v4f* g = (const v4f*)ws;
        for (int i = tid; i < KL * 128; i += BS) {
            sA[i] = g[i];
            sB[i] = g[PLANE_V4 + i];
            sH[i] = g[2 * PLANE_V4 + i];
        }
    }
    for (int i = tid; i < 2 * 4 * NHID * 4; i += BS) (&hsm[0][0][0][0])[i] = 0.0f;
    __syncthreads();

    // per-channel constants
    const float brz = gb[384 + c];
    const float brr = gb[384 + 128 + c];
    const float brh = gb[384 + 256 + c];
    const float xzI = gb[c],       xz0c = xzI + gk[c],       xz1c = xzI + gk[384 + c];
    const float xrI = gb[128 + c], xr0c = xrI + gk[128 + c], xr1c = xrI + gk[384 + 128 + c];
    const float xhI = gb[256 + c], xh0c = xhI + gk[256 + c], xh1c = xhI + gk[384 + 256 + c];
    const float dwc0 = dw[c * 2], dwc1 = dw[c * 2 + 1];
    const float db0 = db[0], db1 = db[1];

    const v4f* lA = sA + c;                         // + k4*128
    const v4f* lB = sB + c;
    const v4f* lH = sH + c;
    const v4f* gA = (const v4f*)ws + c;             // + k4*128
    const v4f* gB = (const v4f*)ws + PLANE_V4 + c;
    const v4f* gH = (const v4f*)ws + 2 * PLANE_V4 + c;
    const float* rkc = rk + c;
    const v4f* hq0 = (const v4f*)&hsm[0][q][0][0];
    const v4f* hq1 = (const v4f*)&hsm[1][q][0][0];

    int   pv[4] = {0, 0, 0, 0};
    float lg[4] = {0.f, 0.f, 0.f, 0.f};
    float pr[4] = {1.f, 1.f, 1.f, 1.f};
    float hop[4] = {0.f, 0.f, 0.f, 0.f};   // h_old for channel c (register-resident)
    int cur = 0;

    for (int t = 0; t < NSTEPS; ++t) {
        float uv[4];
        #pragma unroll
        for (int j = 0; j < 4; ++j)
            uv[j] = u[(size_t)(sbase + j) * NSTEPS + t];

        const v4f* hq = cur ? hq1 : hq0;    // uniform-address h reads (broadcast)

        float az[4], ar[4], ah[4];
        if (TR) {
            v2f az01 = {brz, brz}, az23 = {brz, brz};
            v2f ar01 = {brr, brr}, ar23 = {brr, brr};
            v2f ah01 = {brh, brh}, ah23 = {brh, brh};
            #pragma unroll 4
            for (int k4 = 0; k4 < KL; ++k4) {          // W from LDS
                const v4f zrA = lA[k4 * 128];
                const v4f zrB = lB[k4 * 128];
                const v4f whq = lH[k4 * 128];
                const v4f h0 = hq[4 * k4 + 0];
                const v4f h1 = hq[4 * k4 + 1];
                const v4f h2 = hq[4 * k4 + 2];
                const v4f h3 = hq[4 * k4 + 3];
                K4STEP(zrA, zrB, whq, h0, h1, h2, h3);
            }
            #pragma unroll 4
            for (int k4 = KL; k4 < 32; ++k4) {         // W from L1/L2
                const v4f zrA = gA[k4 * 128];
                const v4f zrB = gB[k4 * 128];
                const v4f whq = gH[k4 * 128];
                const v4f h0 = hq[4 * k4 + 0];
                const v4f h1 = hq[4 * k4 + 1];
                const v4f h2 = hq[4 * k4 + 2];
                const v4f h3 = hq[4 * k4 + 3];
                K4STEP(zrA, zrB, whq, h0, h1, h2, h3);
            }
            az[0] = az01.x; az[1] = az01.y; az[2] = az23.x; az[3] = az23.y;
            ar[0] = ar01.x; ar[1] = ar01.y; ar[2] = ar23.x; ar[3] = ar23.y;
            ah[0] = ah01.x; ah[1] = ah01.y; ah[2] = ah23.x; ah[3] = ah23.y;
        } else {
            #pragma unroll
            for (int j = 0; j < 4; ++j) { az[j] = brz; ar[j] = brr; ah[j] = brh; }
            #pragma unroll 4
            for (int k = 0; k < NHID; ++k) {
                const float wzs = rkc[k * 384];
                const float wrs = rkc[k * 384 + 128];
                const float whs = rkc[k * 384 + 256];
                const v4f hv = hq[k];
                const float hk[4] = {hv.x, hv.y, hv.z, hv.w};
                #pragma unroll
                for (int j = 0; j < 4; ++j) az[j] = fmaf(wzs, hk[j], az[j]);
                #pragma unroll
                for (int j = 0; j < 4; ++j) ar[j] = fmaf(wrs, hk[j], ar[j]);
                #pragma unroll
                for (int j = 0; j < 4; ++j) ah[j] = fmaf(whs, hk[j], ah[j]);
            }
        }

        // ---- gates + state update (h_old from registers)
        float hn[4], p0s[4], p1s[4];
        #pragma unroll
        for (int j = 0; j < 4; ++j) {
            float xz = pv[j] ? xz1c : xz0c;
            float xr = pv[j] ? xr1c : xr0c;
            float xh = pv[j] ? xh1c : xh0c;
            if (t == 0) { xz = xzI; xr = xrI; xh = xhI; }
            const float z  = 1.0f / (1.0f + expf(-(xz + az[j])));
            const float r  = 1.0f / (1.0f + expf(-(xr + ar[j])));
            const float hc = tanhf(xh + r * ah[j]);
            const float hnew = z * hop[j] + (1.0f - z) * hc;
            hn[j] = hnew;
            hop[j] = hnew;
            p0s[j] = hnew * dwc0;
            p1s[j] = hnew * dwc1;
        }
        *(v4f*)&hsm[cur ^ 1][q][c][0] = (v4f){hn[0], hn[1], hn[2], hn[3]};

        // butterfly over channel bits 0..3 (lane bits 0..3): same tree as R11
        #pragma unroll
        for (int j = 0; j < 4; ++j) {
            p0s[j] += swz<0x041F>(p0s[j]);  p1s[j] += swz<0x041F>(p1s[j]);
            p0s[j] += swz<0x081F>(p0s[j]);  p1s[j] += swz<0x081F>(p1s[j]);
            p0s[j] += swz<0x101F>(p0s[j]);  p1s[j] += swz<0x101F>(p1s[j]);
            p0s[j] += swz<0x201F>(p0s[j]);  p1s[j] += swz<0x201F>(p1s[j]);
        }
        const int pb = t & 1;
        if ((lane & 15) == 0) {
            const int g = lane >> 4;
            *(float4*)&part[pb][wv][g][0] = make_float4(p0s[0], p0s[1], p0s[2], p0s[3]);
            *(float4*)&part[pb][wv][g][4] = make_float4(p1s[0], p1s[1], p1s[2], p1s[3]);
        }
        __syncthreads();   // single barrier: h_new + partials visible

        // ---- fold 8 partials (same order as R11)
        float l0[4] = {db0, db0, db0, db0};
        float l1[4] = {db1, db1, db1, db1};
        #pragma unroll
        for (int w = 0; w < 8; ++w) {
            const int hw = w >> 2, g = w & 3;
            const float4 a = *(const float4*)&part[pb][q * 2 + hw][g][0];
            const float4 b = *(const float4*)&part[pb][q * 2 + hw][g][4];
            l0[0] += a.x; l0[1] += a.y; l0[2] += a.z; l0[3] += a.w;
            l1[0] += b.x; l1[1] += b.y; l1[2] += b.z; l1[3] += b.w;
        }

        // ---- softmax / sample / logp (redundant per thread for its quad)
        #pragma unroll
        for (int j = 0; j < 4; ++j) {
            const float mx = fmaxf(l0[j], l1[j]);
            const float e0 = expf(l0[j] - mx);
            const float e1 = expf(l1[j] - mx);
            const float inv = 1.0f / (e0 + e1);
            const float p1v = e1 * inv;
            const int st = (uv[j] < p1v) ? 1 : 0;
            const float psel = st ? p1v : (e0 * inv);
            pr[j] *= (psel + 1e-10f);
            pv[j] = st;
            if (lane == 0 && half == 0)
                out[(size_t)(sbase + j) * NSTEPS + t] = (float)st;
        }
        if ((t & 7) == 7) {
            #pragma unroll
            for (int j = 0; j < 4; ++j) { lg[j] += logf(pr[j]); pr[j] = 1.0f; }
        }
        cur ^= 1;
    }

    if (lane == 0 && half == 0) {
        #pragma unroll
        for (int j = 0; j < 4; ++j)
            out[SAMP_ELEMS + sbase + j] = lg[j];
    }
}

extern "C" void kernel_launch(void* const* d_in, const int* in_sizes, int n_in,
                              void* d_out, int out_size, void* d_ws, size_t ws_size,
                              hipStream_t stream) {
    const float* gk = (const float*)d_in[0];
    const float* rk = (const float*)d_in[1];
    const float* gb = (const float*)d_in[2];
    const float* dw = (const float*)d_in[3];
    const float* db = (const float*)d_in[4];
    const float* u  = (const float*)d_in[5];
    float* out = (float*)d_out;

    if (ws_size >= (size_t)WPK_FLOATS * sizeof(float)) {
        float* ws = (float*)d_ws;
        pack_w_kernel<<<(WPK_FLOATS + 255) / 256, 256, 0, stream>>>(rk, ws);
        vmc_gru_kernel<1><<<NBLK, BS, 0, stream>>>(gk, rk, gb, dw, db, u, ws, out);
    } else {
        vmc_gru_kernel<0><<<NBLK, BS, 0, stream>>>(gk, rk, gb, dw, db, u, rk, out);
    }
}